// Round 2
// baseline (840.027 us; speedup 1.0000x reference)
//
#include <hip/hip_runtime.h>

typedef __bf16 bf16x8 __attribute__((ext_vector_type(8)));
typedef float f32x16 __attribute__((ext_vector_type(16)));

#define K_DIM 256

// ---------------------------------------------------------------------------
// Prep 1: weight-norm a (rows x 256) fp32 matrix. Optionally write:
//   dstb: bf16, k-chunk-major layout per 256-row chunk-block:
//         [r>>8][k>>3][r&255][8]   (256-row blocks, MFMA staging layout;
//         for 256-row matrices this is just [k>>3][row][8])
//   dstf: fp32, row-major (for the cond path, keeps gamma/beta accurate)
// One wave per row.
// ---------------------------------------------------------------------------
__global__ void wn_kernel(const float* __restrict__ v, const float* __restrict__ gv,
                          __bf16* __restrict__ dstb, float* __restrict__ dstf) {
  const int r = blockIdx.x;
  const int l = threadIdx.x;  // 64 threads
  const float* vr = v + (size_t)r * K_DIM;
  float4 p = *reinterpret_cast<const float4*>(vr + l * 4);
  float ss = p.x * p.x + p.y * p.y + p.z * p.z + p.w * p.w;
#pragma unroll
  for (int m = 1; m <= 32; m <<= 1) ss += __shfl_xor(ss, m, 64);
  const float sc = gv[r] * rsqrtf(ss);
  const float a0 = p.x * sc, a1 = p.y * sc, a2 = p.z * sc, a3 = p.w * sc;
  if (dstf != nullptr) {
    float4 o; o.x = a0; o.y = a1; o.z = a2; o.w = a3;
    *reinterpret_cast<float4*>(dstf + (size_t)r * K_DIM + l * 4) = o;
  }
  if (dstb != nullptr) {
    // k = 4l..4l+3 -> kchunk = l>>1, intra-chunk j = (l&1)*4
    __bf16* d = dstb + ((size_t)(r >> 8) << 16) +
                ((size_t)((l >> 1) << 8) + (r & 255)) * 8 + (l & 1) * 4;
    d[0] = (__bf16)a0; d[1] = (__bf16)a1; d[2] = (__bf16)a2; d[3] = (__bf16)a3;
  }
}

// ---------------------------------------------------------------------------
// Prep 2: gbuf[g][0:256]  = gamma = cond @ wnc^T + b_cond + 1   (cols 0:256)
//         gbuf[g][256:512]= beta  = cond @ wnc^T + b_cond       (cols 256:512)
// ---------------------------------------------------------------------------
__global__ void gb_kernel(const float* __restrict__ cond, const float* __restrict__ wncf,
                          const float* __restrict__ bc, float* __restrict__ gbuf) {
  const int gidx = blockIdx.x;
  const int t = threadIdx.x;  // 256
  __shared__ float c[256];
  c[t] = cond[(size_t)gidx * 256 + t];
  __syncthreads();
#pragma unroll
  for (int h = 0; h < 2; ++h) {
    const int o = (h << 8) + t;
    const float* wr = wncf + (size_t)o * 256;
    float s = 0.0f;
#pragma unroll 8
    for (int k = 0; k < 256; k += 4) {
      const float4 w4 = *reinterpret_cast<const float4*>(wr + k);
      s += c[k] * w4.x + c[k + 1] * w4.y + c[k + 2] * w4.z + c[k + 3] * w4.w;
    }
    gbuf[(size_t)gidx * 512 + o] = s + bc[o] + (h == 0 ? 1.0f : 0.0f);
  }
}

// ---------------------------------------------------------------------------
// Main fused kernel v3: persistent-weight design.
//   64 rows/block, 256 threads = 4 waves (2 rowg x 2 colg),
//   wave tile = 32 rows x 128 cols.
// LDS: Wbuf 128 KiB holds the FULL weight matrix of the current stage
//      (W1, W2, or one 256-col half of W3), staged as a contiguous memcpy
//      via global_load_lds. Abuf 32 KiB holds the 64x256 bf16 h tile
//      (XOR-swizzled: slot = row ^ (kc&7) -> conflict-free scalar writes).
// Each GEMM stage runs with ZERO internal barriers (16 K-steps of pure
// ds_read+MFMA). 9 barriers per block total (vs ~64 in v1).
// Stage-1 x is fully preloaded into 128 VGPRs (1 wave/SIMD -> big RF).
// W2 staging (127 of 128 KiB) is issued before LN and hides under it; the
// last 1 KiB of Wbuf doubles as the LN cross-wave reduction scratch.
// ---------------------------------------------------------------------------
__global__ __launch_bounds__(256, 1) void fused_kernel(
    const float* __restrict__ x, const int* __restrict__ bids,
    const __bf16* __restrict__ W1t, const __bf16* __restrict__ W2t,
    const __bf16* __restrict__ W3t, const float* __restrict__ gbuf,
    const float* __restrict__ b2, const float* __restrict__ b3,
    float* __restrict__ out, const int n) {
  __shared__ __bf16 Wbuf[32 * 256 * 8];  // 128 KiB: full stage weights [kc][out][8]
  __shared__ __bf16 Abuf[32 * 64 * 8];   // 32 KiB: h tile, [kc][slot][8] swizzled

  const int t = threadIdx.x;
  const int lane = t & 63;
  const int w = t >> 6;        // 0..3
  const int rowg = w & 1;
  const int colg = w >> 1;
  const int nlo = lane & 31;
  const int g = lane >> 5;
  const int rowbase = rowg << 5;   // 0 / 32
  const int colbase = colg << 7;   // 0 / 128
  const int R = blockIdx.x << 6;

  float* red = reinterpret_cast<float*>(&Wbuf[65024]);  // last 1 KiB of Wbuf

  // Abuf swizzled element index: plane kc (0..31), block-row 0..63.
  auto aidx = [](int kc, int row) { return ((kc << 6) + (row ^ (kc & 7))) << 3; };

  // stage U KiB from src into Wbuf[0..U KiB) as a straight memcpy.
  auto stage = [&](const __bf16* src, int U) {
    for (int u = w; u < U; u += 4) {
      __builtin_amdgcn_global_load_lds(
          (__attribute__((address_space(1))) void*)(src + ((size_t)u << 9) + (lane << 3)),
          (__attribute__((address_space(3))) void*)(&Wbuf[u << 9]), 16, 0, 0);
    }
  };

  f32x16 acc[4];
  auto zero_acc = [&]() {
#pragma unroll
    for (int nt = 0; nt < 4; ++nt)
#pragma unroll
      for (int e = 0; e < 16; ++e) acc[nt][e] = 0.0f;
  };

  // -------- prologue: issue W1 stage + preload x row + bids --------
  stage(W1t, 128);

  int row = R + rowbase + nlo;
  if (row >= n) row = n - 1;
  const float* xrow = x + (size_t)row * K_DIM;
  float4 xp[32];
#pragma unroll
  for (int i = 0; i < 16; ++i) {
    const int kc = (i << 1) + g;
    xp[2 * i]     = *reinterpret_cast<const float4*>(xrow + (kc << 3));
    xp[2 * i + 1] = *reinterpret_cast<const float4*>(xrow + (kc << 3) + 4);
  }
  int bidv[16];
#pragma unroll
  for (int reg = 0; reg < 16; ++reg) {
    const int rl = (reg & 3) + ((reg >> 2) << 3) + (g << 2);
    int rg = R + rowbase + rl;
    if (rg >= n) rg = n - 1;
    bidv[reg] = bids[rg];
  }
  __syncthreads();  // B0: W1 + x + bids landed

  // -------- stage 1: s1 = x @ W1^T  (barrier-free K loop) --------
  zero_acc();
#pragma unroll
  for (int ks = 0; ks < 16; ++ks) {
    const int kc = (ks << 1) + g;
    const float4 p = xp[2 * ks], q = xp[2 * ks + 1];
    bf16x8 a;
    a[0] = (__bf16)p.x; a[1] = (__bf16)p.y; a[2] = (__bf16)p.z; a[3] = (__bf16)p.w;
    a[4] = (__bf16)q.x; a[5] = (__bf16)q.y; a[6] = (__bf16)q.z; a[7] = (__bf16)q.w;
#pragma unroll
    for (int nt = 0; nt < 4; ++nt) {
      const bf16x8 b = *reinterpret_cast<const bf16x8*>(
          &Wbuf[((kc << 8) + colbase + (nt << 5) + nlo) << 3]);
      acc[nt] = __builtin_amdgcn_mfma_f32_32x32x16_bf16(a, b, acc[nt], 0, 0, 0);
    }
  }
  __syncthreads();   // B1: all waves done reading W1
  stage(W2t, 127);   // issue W2 (all but last 1 KiB; red lives there) — hides under LN

  // -------- layernorm (cross-colg via red) + FiLM + relu -> Abuf --------
  {
    // partial sums over this wave's 128 cols, reduced across the 32 nlo lanes
#pragma unroll
    for (int reg = 0; reg < 16; ++reg) {
      float s = 0.0f, q = 0.0f;
#pragma unroll
      for (int nt = 0; nt < 4; ++nt) {
        const float v = acc[nt][reg];
        s += v; q += v * v;
      }
#pragma unroll
      for (int m = 1; m <= 16; m <<= 1) {
        s += __shfl_xor(s, m, 64);
        q += __shfl_xor(q, m, 64);
      }
      if (nlo == 0) {
        const int rl = (reg & 3) + ((reg >> 2) << 3) + (g << 2);
        const int rowi = rowbase + rl;
        float2 sq; sq.x = s; sq.y = q;
        *reinterpret_cast<float2*>(&red[(rowi << 2) + (colg << 1)]) = sq;
      }
    }
    __syncthreads();  // B2: red visible (also drains most of W2 stage)
#pragma unroll
    for (int reg = 0; reg < 16; ++reg) {
      const int rl = (reg & 3) + ((reg >> 2) << 3) + (g << 2);
      const int rowi = rowbase + rl;
      const float4 r4 = *reinterpret_cast<const float4*>(&red[rowi << 2]);
      const float s = r4.x + r4.z, q = r4.y + r4.w;
      const float mean = s * (1.0f / 256.0f);
      const float var = q * (1.0f / 256.0f) - mean * mean;
      const float rsv = rsqrtf(var + 1e-5f);
      const float* grow = gbuf + ((size_t)bidv[reg] << 9);
#pragma unroll
      for (int nt = 0; nt < 4; ++nt) {
        const int col = colbase + (nt << 5) + nlo;
        float v = (acc[nt][reg] - mean) * rsv;
        v = v * grow[col] + grow[256 + col];
        v = v > 0.0f ? v : 0.0f;
        Abuf[aidx(col >> 3, rowi) + (col & 7)] = (__bf16)v;
      }
    }
  }
  __syncthreads();  // B3: red reads done by all waves; Abuf complete
  if (w == 3) {     // last 1 KiB of W2 (overwrites red region)
    __builtin_amdgcn_global_load_lds(
        (__attribute__((address_space(1))) void*)(W2t + ((size_t)127 << 9) + (lane << 3)),
        (__attribute__((address_space(3))) void*)(&Wbuf[127 << 9]), 16, 0, 0);
  }
  __syncthreads();  // B4: W2 fully resident

  // -------- stage 2: relu(h @ W2^T + b2) -> Abuf (barrier-free K loop) ----
  zero_acc();
#pragma unroll
  for (int ks = 0; ks < 16; ++ks) {
    const int kc = (ks << 1) + g;
    const bf16x8 a = *reinterpret_cast<const bf16x8*>(&Abuf[aidx(kc, rowbase + nlo)]);
#pragma unroll
    for (int nt = 0; nt < 4; ++nt) {
      const bf16x8 b = *reinterpret_cast<const bf16x8*>(
          &Wbuf[((kc << 8) + colbase + (nt << 5) + nlo) << 3]);
      acc[nt] = __builtin_amdgcn_mfma_f32_32x32x16_bf16(a, b, acc[nt], 0, 0, 0);
    }
  }
  __syncthreads();   // B5: W2 + Abuf reads done
  stage(W3t, 128);   // issue W3 half 0 — hides under epilogue
  {
    float b2v[4];
#pragma unroll
    for (int nt = 0; nt < 4; ++nt) b2v[nt] = b2[colbase + (nt << 5) + nlo];
#pragma unroll
    for (int reg = 0; reg < 16; ++reg) {
      const int rl = (reg & 3) + ((reg >> 2) << 3) + (g << 2);
      const int rowi = rowbase + rl;
#pragma unroll
      for (int nt = 0; nt < 4; ++nt) {
        const int col = colbase + (nt << 5) + nlo;
        float v = acc[nt][reg] + b2v[nt];
        v = v > 0.0f ? v : 0.0f;
        Abuf[aidx(col >> 3, rowi) + (col & 7)] = (__bf16)v;
      }
    }
  }
  __syncthreads();  // B6: W3h0 resident + Abuf(h2) complete

  // -------- stage 3 half 0: out[:, 0:256] --------
  zero_acc();
#pragma unroll
  for (int ks = 0; ks < 16; ++ks) {
    const int kc = (ks << 1) + g;
    const bf16x8 a = *reinterpret_cast<const bf16x8*>(&Abuf[aidx(kc, rowbase + nlo)]);
#pragma unroll
    for (int nt = 0; nt < 4; ++nt) {
      const bf16x8 b = *reinterpret_cast<const bf16x8*>(
          &Wbuf[((kc << 8) + colbase + (nt << 5) + nlo) << 3]);
      acc[nt] = __builtin_amdgcn_mfma_f32_32x32x16_bf16(a, b, acc[nt], 0, 0, 0);
    }
  }
  __syncthreads();           // B7: W3h0 reads done
  stage(W3t + 65536, 128);   // issue W3 half 1 — hides under half-0 epilogue/stores
  {
    float b3v[4];
#pragma unroll
    for (int nt = 0; nt < 4; ++nt) b3v[nt] = b3[colbase + (nt << 5) + nlo];
#pragma unroll
    for (int reg = 0; reg < 16; ++reg) {
      const int rl = (reg & 3) + ((reg >> 2) << 3) + (g << 2);
      const int rglob = R + rowbase + rl;
      if (rglob < n) {
        float* orow = out + (size_t)rglob * 512;
#pragma unroll
        for (int nt = 0; nt < 4; ++nt)
          orow[colbase + (nt << 5) + nlo] = acc[nt][reg] + b3v[nt];
      }
    }
  }
  __syncthreads();  // B8: W3h1 resident

  // -------- stage 3 half 1: out[:, 256:512] --------
  zero_acc();
#pragma unroll
  for (int ks = 0; ks < 16; ++ks) {
    const int kc = (ks << 1) + g;
    const bf16x8 a = *reinterpret_cast<const bf16x8*>(&Abuf[aidx(kc, rowbase + nlo)]);
#pragma unroll
    for (int nt = 0; nt < 4; ++nt) {
      const bf16x8 b = *reinterpret_cast<const bf16x8*>(
          &Wbuf[((kc << 8) + colbase + (nt << 5) + nlo) << 3]);
      acc[nt] = __builtin_amdgcn_mfma_f32_32x32x16_bf16(a, b, acc[nt], 0, 0, 0);
    }
  }
  {
    float b3v[4];
#pragma unroll
    for (int nt = 0; nt < 4; ++nt) b3v[nt] = b3[256 + colbase + (nt << 5) + nlo];
#pragma unroll
    for (int reg = 0; reg < 16; ++reg) {
      const int rl = (reg & 3) + ((reg >> 2) << 3) + (g << 2);
      const int rglob = R + rowbase + rl;
      if (rglob < n) {
        float* orow = out + (size_t)rglob * 512 + 256;
#pragma unroll
        for (int nt = 0; nt < 4; ++nt)
          orow[colbase + (nt << 5) + nlo] = acc[nt][reg] + b3v[nt];
      }
    }
  }
}

extern "C" void kernel_launch(void* const* d_in, const int* in_sizes, int n_in,
                              void* d_out, int out_size, void* d_ws, size_t ws_size,
                              hipStream_t stream) {
  const float* x      = (const float*)d_in[0];
  const float* cond   = (const float*)d_in[1];
  const int*   bids   = (const int*)d_in[2];
  const float* v_cond = (const float*)d_in[3];
  const float* g_cond = (const float*)d_in[4];
  const float* b_cond = (const float*)d_in[5];
  const float* v1     = (const float*)d_in[6];
  const float* g1     = (const float*)d_in[7];
  const float* v2     = (const float*)d_in[8];
  const float* g2     = (const float*)d_in[9];
  const float* b2     = (const float*)d_in[10];
  const float* v3     = (const float*)d_in[11];
  const float* g3     = (const float*)d_in[12];
  const float* b3     = (const float*)d_in[13];
  float* out = (float*)d_out;
  const int n = in_sizes[0] / K_DIM;

  // workspace layout
  char* ws = (char*)d_ws;
  __bf16* W1t = (__bf16*)ws;               // 256x256 bf16, k-chunk-major (128 KB)
  __bf16* W2t = W1t + 65536;               // 128 KB
  __bf16* W3t = W2t + 65536;               // 512x256 bf16: [half][kc][256][8] (256 KB)
  float* wncf = (float*)(W3t + 131072);    // 512x256 fp32 normalized v_cond (512 KB)
  float* gbuf = wncf + 131072;             // 256x512 fp32 gamma|beta (512 KB)

  wn_kernel<<<256, 64, 0, stream>>>(v1, g1, W1t, nullptr);
  wn_kernel<<<256, 64, 0, stream>>>(v2, g2, W2t, nullptr);
  wn_kernel<<<512, 64, 0, stream>>>(v3, g3, W3t, nullptr);
  wn_kernel<<<512, 64, 0, stream>>>(v_cond, g_cond, nullptr, wncf);
  gb_kernel<<<256, 256, 0, stream>>>(cond, wncf, b_cond, gbuf);

  const int nb = (n + 63) / 64;
  fused_kernel<<<nb, 256, 0, stream>>>(x, bids, W1t, W2t, W3t, gbuf, b2, b3, out, n);
}